// Round 2
// baseline (151.850 us; speedup 1.0000x reference)
//
#include <hip/hip_runtime.h>

// Reduced problem: out[n] depends only on x0 = node_vec[:, :128], emb, W1_l0[:, :, :128],
// b1[:128], W2, b2, W3, b3, W4, b4.  y1/y2/gates are dead code in the reference.
//
// R12 -> R13: MEASUREMENT ROUND. main_kernel is idempotent (pure overwrite of `out`),
// so it is launched 4x. dur_us_new - dur_us_old = 3 * T_main, amplifying main's true
// cost 3x above the +-2.5us noise band. Kernel bodies are byte-identical to R12.
//   T_main <= ~12us  -> harness fills dominate the envelope -> roofline.
//   T_main >= ~30us  -> ~30us headroom; main rows become visible in rocprof top-5.

typedef _Float16 h8  __attribute__((ext_vector_type(8)));
typedef _Float16 h2  __attribute__((ext_vector_type(2)));
typedef float    f32x4  __attribute__((ext_vector_type(4)));
typedef float    f32x16 __attribute__((ext_vector_type(16)));
typedef unsigned int u32;

static __device__ __forceinline__ u32 pack2h(float a, float b) {
    h2 t = {(_Float16)a, (_Float16)b};
    return __builtin_bit_cast(u32, t);
}
static __device__ __forceinline__ f32x4 mfma16(uint4 a, uint4 b, f32x4 c) {
    return __builtin_amdgcn_mfma_f32_16x16x32_f16(
        __builtin_bit_cast(h8, a), __builtin_bit_cast(h8, b), c, 0, 0, 0);
}
static __device__ __forceinline__ f32x16 mfma32(uint4 a, uint4 b, f32x16 c) {
    return __builtin_amdgcn_mfma_f32_32x32x16_f16(
        __builtin_bit_cast(h8, a), __builtin_bit_cast(h8, b), c, 0, 0, 0);
}
// A-frag element j = xh * ee[j]
static __device__ __forceinline__ uint4 mk_afrag(_Float16 xh, const h2* ee) {
    h2 xx = {xh, xh};
    uint4 r;
    r.x = __builtin_bit_cast(u32, (h2)(xx * ee[0]));
    r.y = __builtin_bit_cast(u32, (h2)(xx * ee[1]));
    r.z = __builtin_bit_cast(u32, (h2)(xx * ee[2]));
    r.w = __builtin_bit_cast(u32, (h2)(xx * ee[3]));
    return r;
}

// ---------------------------------------------------------------------------
// Prep. Blocks 0..127: W1T in 32x32x16 B-frag order, step = K/16 = x-column i:
//   W1T[step][t][lane][j] = f16(W1[K = step*16 + (lane>>5)*8 + j][t*32 + (lane&31)])
// Blocks 128..191: W2T in 16x16x32 B-frag order:
//   W2T[kc][lane][j] = f16(W2[kc*32 + (lane>>4)*8 + j][lane&15])
// ---------------------------------------------------------------------------
__global__ __launch_bounds__(256) void prep_kernel(
        const float* __restrict__ W1, const float* __restrict__ W2,
        _Float16* __restrict__ W1T, _Float16* __restrict__ W2T) {
    const int tid = threadIdx.x;
    if (blockIdx.x < 128) {
        const int step = blockIdx.x;
        __shared__ float l1[16 * 132];
        for (int idx = tid; idx < 512; idx += 256) {     // 16 rows x 32 float4
            int row = idx >> 5, c4 = idx & 31;
            float4 v = *(const float4*)(W1 + (size_t)(step * 16 + row) * 224 + c4 * 4);
            *(float4*)(l1 + row * 132 + c4 * 4) = v;
        }
        __syncthreads();
        const int t = tid >> 6, lane = tid & 63;
        const int half = lane >> 5, col = t * 32 + (lane & 31);
        u32 w[4];
#pragma unroll
        for (int jj = 0; jj < 4; ++jj)
            w[jj] = pack2h(l1[(half * 8 + 2 * jj) * 132 + col],
                           l1[(half * 8 + 2 * jj + 1) * 132 + col]);
        *(uint4*)(W1T + (size_t)((step * 4 + t) * 64 + lane) * 8) =
            make_uint4(w[0], w[1], w[2], w[3]);
    } else {
        const int kc = blockIdx.x - 128;                 // 0..63
        __shared__ float l2[32 * 20];
        if (tid < 128) {
            int row = tid >> 2, c4 = tid & 3;
            float4 v = *(const float4*)(W2 + (size_t)(kc * 32 + row) * 16 + c4 * 4);
            *(float4*)(l2 + row * 20 + c4 * 4) = v;
        }
        __syncthreads();
        if (tid < 64) {
            int lane = tid, q = lane >> 4, cc = lane & 15;
            u32 w[4];
#pragma unroll
            for (int jj = 0; jj < 4; ++jj)
                w[jj] = pack2h(l2[(q * 8 + 2 * jj) * 20 + cc],
                               l2[(q * 8 + 2 * jj + 1) * 20 + cc]);
            *(uint4*)(W2T + (size_t)kc * 512 + lane * 8) = make_uint4(w[0], w[1], w[2], w[3]);
        }
    }
}

// ---------------------------------------------------------------------------
// Main: 64 nodes/block, 16 waves, (1024,4) -> 1 block/CU, 128-VGPR cap.
// Phase1 (32x32x16): wave = (kh = wave>>2 K-quarter) x (t = wave&3 col-tile);
//   2 m-tiles x 32 nodes x 32 cols x 32 steps; kh=1..3 -> f32 partial sets,
//   kh=0 single-shot reduce + silu.
// Phase2 (16x16x32): wave = (ng node-group) x (ks K-quarter).
// Phase3: 1024 threads.
// ---------------------------------------------------------------------------
__global__ __launch_bounds__(1024, 4) void main_kernel(
        const float* __restrict__ node_vec, const float* __restrict__ emb,
        const _Float16* __restrict__ W1T, const _Float16* __restrict__ W2T,
        const float* __restrict__ b1, const float* __restrict__ b2,
        const float* __restrict__ W3, const float* __restrict__ b3,
        const float* __restrict__ W4, const float* __restrict__ b4,
        float* __restrict__ out) {
    __shared__ __align__(16) _Float16 xs[64 * 136];        // x0 -> later silu(s0)
    __shared__ __align__(16) float sets[3 * 64 * 128];     // kh f32 partials / midp+mids
    __shared__ float b1s[128];
    __shared__ float b2s[16];
    __shared__ float w3s[256];
    __shared__ float b3s[16];
    __shared__ float w4s[16];
    __shared__ float b4s[1];

    float* midp = sets;                // phase >= 2 overlay
    float* mids = sets + 4352;         // byte offset 17408

    const int tid  = threadIdx.x;
    const int wave = tid >> 6, lane = tid & 63;
    const int l31 = lane & 31, half = lane >> 5;
    const int nodeBase = blockIdx.x * 64;

    // stage x0 (cols 0..127) f16 row-major, stride 136
    for (int idx = tid; idx < 2048; idx += 1024) {
        int row = idx >> 5, c4 = idx & 31;
        float4 v = *(const float4*)(node_vec + (size_t)(nodeBase + row) * 480 + c4 * 4);
        u32 p0 = pack2h(v.x, v.y), p1 = pack2h(v.z, v.w);
        *(uint2*)(xs + row * 136 + c4 * 4) = make_uint2(p0, p1);
    }
    if (tid < 256) w3s[tid] = W3[tid];
    if (tid >= 256 && tid < 384) b1s[tid - 256] = b1[tid - 256];
    if (tid >= 384 && tid < 400) b2s[tid - 384] = b2[tid - 384];
    if (tid < 16) { b3s[tid] = b3[tid]; w4s[tid] = W4[tid]; }
    if (tid == 0) b4s[0] = b4[0];

    // phase-1 emb slices: m-tile mt node = nodeBase + mt*32 + l31, a = half*8 + j
    h2 ee0[4], ee1[4];
#pragma unroll
    for (int mt = 0; mt < 2; ++mt) {
        const float* ep = emb + (size_t)(nodeBase + mt * 32 + l31) * 16 + half * 8;
        float4 v0 = *(const float4*)ep;
        float4 v1 = *(const float4*)(ep + 4);
        h2* ee = mt ? ee1 : ee0;
        ee[0] = (h2){(_Float16)v0.x, (_Float16)v0.y};
        ee[1] = (h2){(_Float16)v0.z, (_Float16)v0.w};
        ee[2] = (h2){(_Float16)v1.x, (_Float16)v1.y};
        ee[3] = (h2){(_Float16)v1.z, (_Float16)v1.w};
    }
    __syncthreads();

    // ---------------- Phase 1: 64 nodes x 32 cols x 32 steps (K/16) per wave
    const int kh = wave >> 2;                      // K-quarter (32 steps)
    const int t  = wave & 3;                       // 32-col tile
    f32x16 acc0 = {0.f}, acc1 = {0.f};
#pragma unroll
    for (int r = 0; r < 16; ++r) { acc0[r] = 0.f; acc1[r] = 0.f; }

    const uint4* bp = (const uint4*)W1T + ((kh * 32 * 4 + t) * 64 + lane);
    const _Float16* xr0 = xs + (0 * 32 + l31) * 136 + kh * 32;
    const _Float16* xr1 = xs + (1 * 32 + l31) * 136 + kh * 32;

    uint4 ring[8];
#pragma unroll
    for (int r = 0; r < 8; ++r) ring[r] = bp[r * 256];
    h8 xc0, xc1, xn0, xn1;
    xc0 = *(const h8*)xr0;       xc1 = *(const h8*)xr1;
    xn0 = *(const h8*)(xr0 + 8); xn1 = *(const h8*)(xr1 + 8);

#pragma unroll
    for (int bb = 0; bb < 4; ++bb) {
#pragma unroll
        for (int u = 0; u < 8; ++u) {
            uint4 cur = ring[u];
            if (bb < 3) ring[u] = bp[(bb * 8 + u + 8) * 256];   // no tail overshoot
            acc0 = mfma32(mk_afrag(xc0[u], ee0), cur, acc0);
            acc1 = mfma32(mk_afrag(xc1[u], ee1), cur, acc1);
        }
        xc0 = xn0; xc1 = xn1;
        if (bb + 2 < 4) {
            xn0 = *(const h8*)(xr0 + (bb + 2) * 8);
            xn1 = *(const h8*)(xr1 + (bb + 2) * 8);
        }
    }

    // C layout (32x32): col = t*32 + l31, row = (r&3) + 8*(r>>2) + 4*half
    const int colG = t * 32 + l31;
#define ROWOF(r) (((r) & 3) + 8 * ((r) >> 2) + 4 * half)

    // kh=1..3 store f32 partials; kh=0 single-shot reduce + silu
    if (kh >= 1) {
        float* st = sets + (kh - 1) * (64 * 128);
#pragma unroll
        for (int r = 0; r < 16; ++r) {
            int row = ROWOF(r);
            st[row * 128 + colG]        = acc0[r];
            st[(row + 32) * 128 + colG] = acc1[r];
        }
    }
    __syncthreads();

    const float inv2048 = 0.022097086912079608f;   // 1/sqrt(128*16)
    if (kh == 0) {
        const float bb1v = b1s[colG];
        const float* s1p = sets;
        const float* s2p = sets + 64 * 128;
        const float* s3p = sets + 2 * 64 * 128;
#pragma unroll
        for (int r = 0; r < 16; ++r) {
            int row = ROWOF(r);
            int o0 = row * 128 + colG, o1 = (row + 32) * 128 + colG;
            float s0 = (acc0[r] + s1p[o0] + s2p[o0] + s3p[o0]) * inv2048 + bb1v;
            float s1 = (acc1[r] + s1p[o1] + s2p[o1] + s3p[o1]) * inv2048 + bb1v;
            xs[row * 136 + colG]        = (_Float16)(s0 / (1.f + __expf(-s0)));
            xs[(row + 32) * 136 + colG] = (_Float16)(s1 / (1.f + __expf(-s1)));
        }
    }
    __syncthreads();   // scs ready; sets free for midp overlay

    // ---------------- Phase 2: (silu(s0) (x) emb) @ W2T  (16x16x32)
    {
        const int ng = wave >> 2, ks = wave & 3;
        const int q = lane >> 4, c = lane & 15;
        const int ih = q >> 1, aodd = q & 1;
        h2 ee[4];
        {
            const float* ep = emb + (size_t)(nodeBase + ng * 16 + c) * 16 + aodd * 8;
            float4 v0 = *(const float4*)ep;
            float4 v1 = *(const float4*)(ep + 4);
            ee[0] = (h2){(_Float16)v0.x, (_Float16)v0.y};
            ee[1] = (h2){(_Float16)v0.z, (_Float16)v0.w};
            ee[2] = (h2){(_Float16)v1.x, (_Float16)v1.y};
            ee[3] = (h2){(_Float16)v1.z, (_Float16)v1.w};
        }
        const _Float16* srow = xs + (ng * 16 + c) * 136;   // col = 2*k2global + ih
        const uint4* b2p = (const uint4*)W2T + lane;
        f32x4 m0 = (f32x4){0.f, 0.f, 0.f, 0.f};
        uint4 wb[4];
#pragma unroll
        for (int u = 0; u < 4; ++u) wb[u] = b2p[(ks * 16 + u) * 64];
#pragma unroll
        for (int k2 = 0; k2 < 16; ++k2) {
            uint4 cur = wb[k2 & 3];
            if (k2 + 4 < 16) wb[k2 & 3] = b2p[(ks * 16 + k2 + 4) * 64];
            _Float16 sv = srow[(ks * 16 + k2) * 2 + ih];
            m0 = mfma16(mk_afrag(sv, ee), cur, m0);
        }
#pragma unroll
        for (int r = 0; r < 4; ++r) {
            int node = ng * 16 + q * 4 + r;
            midp[(ks * 64 + node) * 17 + c] = m0[r];
        }
    }
    __syncthreads();

    // reduce 4 K-quarters; 1024 threads = 64 nodes x 16 cols
    {
        int node = tid >> 4, col = tid & 15;
        float m = midp[node * 17 + col] + midp[(64 + node) * 17 + col]
                + midp[(128 + node) * 17 + col] + midp[(192 + node) * 17 + col];
        mids[node * 17 + col] = m * inv2048 + b2s[col];
    }
    __syncthreads();

    // ---------------- Phase 3: h = silu(mid@W3/4 + b3); out = h@W4/4 + b4
    {
        int n = tid >> 4, jj = tid & 15;
        float a = 0.f;
#pragma unroll
        for (int cc = 0; cc < 16; ++cc) a += mids[n * 17 + cc] * w3s[cc * 16 + jj];
        a = a * 0.25f + b3s[jj];
        float hh = a / (1.f + __expf(-a));
        float po = hh * w4s[jj];
        po += __shfl_xor(po, 1);
        po += __shfl_xor(po, 2);
        po += __shfl_xor(po, 4);
        po += __shfl_xor(po, 8);
        if (jj == 0) out[nodeBase + n] = po * 0.25f + b4s[0];
    }
#undef ROWOF
}

extern "C" void kernel_launch(void* const* d_in, const int* in_sizes, int n_in,
                              void* d_out, int out_size, void* d_ws, size_t ws_size,
                              hipStream_t stream) {
    const float* node_vec = (const float*)d_in[0];
    const float* emb      = (const float*)d_in[1];
    const float* W1       = (const float*)d_in[2];
    const float* b1v      = (const float*)d_in[5];
    const float* W2       = (const float*)d_in[6];
    const float* b2v      = (const float*)d_in[7];
    const float* W3       = (const float*)d_in[8];
    const float* b3v      = (const float*)d_in[9];
    const float* W4       = (const float*)d_in[10];
    const float* b4v      = (const float*)d_in[11];

    _Float16* W1T = (_Float16*)d_ws;          // 128*4*64*8 halves = 512 KB
    _Float16* W2T = W1T + 128 * 4 * 64 * 8;   // 64*512 halves = 64 KB
    float* out = (float*)d_out;

    prep_kernel<<<192, 256, 0, stream>>>(W1, W2, W1T, W2T);
    // MEASUREMENT: main is idempotent (pure overwrite of `out`); 4 launches add
    // exactly 3*T_main to dur_us, amplifying main's true cost above the noise band.
    for (int rep = 0; rep < 4; ++rep)
        main_kernel<<<256, 1024, 0, stream>>>(node_vec, emb, W1T, W2T,
                                              b1v, b2v, W3, b3v, W4, b4v, out);
}

// Round 3
// 107.675 us; speedup vs baseline: 1.4103x; 1.4103x over previous
//
#include <hip/hip_runtime.h>

// Reduced problem: out[n] depends only on x0 = node_vec[:, :128], emb, W1_l0[:, :, :128],
// b1[:128], W2, b2, W3, b3, W4, b4.  y1/y2/gates are dead code in the reference.
//
// R13 measurement: T_main = (151.85-109.12)/3 = 14.2us; envelope = ~85us harness fills
// (at HBM roofline) + main + prep + ~5us overhead.
// R13 -> R14:
//  (1) kh-reduce parallelized 4x: ALL waves store f32 partials (4 sets, LDS 150 KB),
//      then flat 1024-thread reduce (8 outputs, 32 conflict-free reads, 8 exp each)
//      instead of 4 waves doing 96 reads + 32 exp while 12 waves idle.
//  (2) ring[8] W1T prefetch hoisted above the staging barrier: first-load L2 latency
//      (~200cy) hides under the barrier instead of stalling phase-1 entry.
//  (3) launcher back to a single main launch.

typedef _Float16 h8  __attribute__((ext_vector_type(8)));
typedef _Float16 h2  __attribute__((ext_vector_type(2)));
typedef float    f32x4  __attribute__((ext_vector_type(4)));
typedef float    f32x16 __attribute__((ext_vector_type(16)));
typedef unsigned int u32;

static __device__ __forceinline__ u32 pack2h(float a, float b) {
    h2 t = {(_Float16)a, (_Float16)b};
    return __builtin_bit_cast(u32, t);
}
static __device__ __forceinline__ f32x4 mfma16(uint4 a, uint4 b, f32x4 c) {
    return __builtin_amdgcn_mfma_f32_16x16x32_f16(
        __builtin_bit_cast(h8, a), __builtin_bit_cast(h8, b), c, 0, 0, 0);
}
static __device__ __forceinline__ f32x16 mfma32(uint4 a, uint4 b, f32x16 c) {
    return __builtin_amdgcn_mfma_f32_32x32x16_f16(
        __builtin_bit_cast(h8, a), __builtin_bit_cast(h8, b), c, 0, 0, 0);
}
// A-frag element j = xh * ee[j]
static __device__ __forceinline__ uint4 mk_afrag(_Float16 xh, const h2* ee) {
    h2 xx = {xh, xh};
    uint4 r;
    r.x = __builtin_bit_cast(u32, (h2)(xx * ee[0]));
    r.y = __builtin_bit_cast(u32, (h2)(xx * ee[1]));
    r.z = __builtin_bit_cast(u32, (h2)(xx * ee[2]));
    r.w = __builtin_bit_cast(u32, (h2)(xx * ee[3]));
    return r;
}

// ---------------------------------------------------------------------------
// Prep. Blocks 0..127: W1T in 32x32x16 B-frag order, step = K/16 = x-column i:
//   W1T[step][t][lane][j] = f16(W1[K = step*16 + (lane>>5)*8 + j][t*32 + (lane&31)])
// Blocks 128..191: W2T in 16x16x32 B-frag order:
//   W2T[kc][lane][j] = f16(W2[kc*32 + (lane>>4)*8 + j][lane&15])
// ---------------------------------------------------------------------------
__global__ __launch_bounds__(256) void prep_kernel(
        const float* __restrict__ W1, const float* __restrict__ W2,
        _Float16* __restrict__ W1T, _Float16* __restrict__ W2T) {
    const int tid = threadIdx.x;
    if (blockIdx.x < 128) {
        const int step = blockIdx.x;
        __shared__ float l1[16 * 132];
        for (int idx = tid; idx < 512; idx += 256) {     // 16 rows x 32 float4
            int row = idx >> 5, c4 = idx & 31;
            float4 v = *(const float4*)(W1 + (size_t)(step * 16 + row) * 224 + c4 * 4);
            *(float4*)(l1 + row * 132 + c4 * 4) = v;
        }
        __syncthreads();
        const int t = tid >> 6, lane = tid & 63;
        const int half = lane >> 5, col = t * 32 + (lane & 31);
        u32 w[4];
#pragma unroll
        for (int jj = 0; jj < 4; ++jj)
            w[jj] = pack2h(l1[(half * 8 + 2 * jj) * 132 + col],
                           l1[(half * 8 + 2 * jj + 1) * 132 + col]);
        *(uint4*)(W1T + (size_t)((step * 4 + t) * 64 + lane) * 8) =
            make_uint4(w[0], w[1], w[2], w[3]);
    } else {
        const int kc = blockIdx.x - 128;                 // 0..63
        __shared__ float l2[32 * 20];
        if (tid < 128) {
            int row = tid >> 2, c4 = tid & 3;
            float4 v = *(const float4*)(W2 + (size_t)(kc * 32 + row) * 16 + c4 * 4);
            *(float4*)(l2 + row * 20 + c4 * 4) = v;
        }
        __syncthreads();
        if (tid < 64) {
            int lane = tid, q = lane >> 4, cc = lane & 15;
            u32 w[4];
#pragma unroll
            for (int jj = 0; jj < 4; ++jj)
                w[jj] = pack2h(l2[(q * 8 + 2 * jj) * 20 + cc],
                               l2[(q * 8 + 2 * jj + 1) * 20 + cc]);
            *(uint4*)(W2T + (size_t)kc * 512 + lane * 8) = make_uint4(w[0], w[1], w[2], w[3]);
        }
    }
}

// ---------------------------------------------------------------------------
// Main: 64 nodes/block, 16 waves, (1024,4) -> 1 block/CU, 128-VGPR cap.
// Phase1 (32x32x16): wave = (kh = wave>>2 K-quarter) x (t = wave&3 col-tile);
//   2 m-tiles x 32 nodes x 32 cols x 32 steps; ALL kh -> f32 partial sets,
//   flat 1024-thread reduce + silu.
// Phase2 (16x16x32): wave = (ng node-group) x (ks K-quarter).
// Phase3: 1024 threads.
// LDS: xs 17.4 KB | sets 4 x 64x128 f32 = 128 KB (phase2 overlays midp+mids)
//      | b1s/b2s/w3s/b3s/w4s/b4s.  ~150 KB total, 1 block/CU.
// ---------------------------------------------------------------------------
__global__ __launch_bounds__(1024, 4) void main_kernel(
        const float* __restrict__ node_vec, const float* __restrict__ emb,
        const _Float16* __restrict__ W1T, const _Float16* __restrict__ W2T,
        const float* __restrict__ b1, const float* __restrict__ b2,
        const float* __restrict__ W3, const float* __restrict__ b3,
        const float* __restrict__ W4, const float* __restrict__ b4,
        float* __restrict__ out) {
    __shared__ __align__(16) _Float16 xs[64 * 136];        // x0 -> later silu(s0)
    __shared__ __align__(16) float sets[4 * 64 * 128];     // kh f32 partials / midp+mids
    __shared__ float b1s[128];
    __shared__ float b2s[16];
    __shared__ float w3s[256];
    __shared__ float b3s[16];
    __shared__ float w4s[16];
    __shared__ float b4s[1];

    float* midp = sets;                // phase >= 2 overlay
    float* mids = sets + 4352;         // byte offset 17408

    const int tid  = threadIdx.x;
    const int wave = tid >> 6, lane = tid & 63;
    const int l31 = lane & 31, half = lane >> 5;
    const int nodeBase = blockIdx.x * 64;

    // stage x0 (cols 0..127) f16 row-major, stride 136
    for (int idx = tid; idx < 2048; idx += 1024) {
        int row = idx >> 5, c4 = idx & 31;
        float4 v = *(const float4*)(node_vec + (size_t)(nodeBase + row) * 480 + c4 * 4);
        u32 p0 = pack2h(v.x, v.y), p1 = pack2h(v.z, v.w);
        *(uint2*)(xs + row * 136 + c4 * 4) = make_uint2(p0, p1);
    }
    if (tid < 256) w3s[tid] = W3[tid];
    if (tid >= 256 && tid < 384) b1s[tid - 256] = b1[tid - 256];
    if (tid >= 384 && tid < 400) b2s[tid - 384] = b2[tid - 384];
    if (tid < 16) { b3s[tid] = b3[tid]; w4s[tid] = W4[tid]; }
    if (tid == 0) b4s[0] = b4[0];

    // phase-1 emb slices: m-tile mt node = nodeBase + mt*32 + l31, a = half*8 + j
    h2 ee0[4], ee1[4];
#pragma unroll
    for (int mt = 0; mt < 2; ++mt) {
        const float* ep = emb + (size_t)(nodeBase + mt * 32 + l31) * 16 + half * 8;
        float4 v0 = *(const float4*)ep;
        float4 v1 = *(const float4*)(ep + 4);
        h2* ee = mt ? ee1 : ee0;
        ee[0] = (h2){(_Float16)v0.x, (_Float16)v0.y};
        ee[1] = (h2){(_Float16)v0.z, (_Float16)v0.w};
        ee[2] = (h2){(_Float16)v1.x, (_Float16)v1.y};
        ee[3] = (h2){(_Float16)v1.z, (_Float16)v1.w};
    }

    // ring prefetch HOISTED above the barrier: W1T loads have no LDS dependency,
    // so their L2 latency hides under the staging barrier.
    const int kh = wave >> 2;                      // K-quarter (32 steps)
    const int t  = wave & 3;                       // 32-col tile
    const uint4* bp = (const uint4*)W1T + ((kh * 32 * 4 + t) * 64 + lane);
    uint4 ring[8];
#pragma unroll
    for (int r = 0; r < 8; ++r) ring[r] = bp[r * 256];

    __syncthreads();

    // ---------------- Phase 1: 64 nodes x 32 cols x 32 steps (K/16) per wave
    f32x16 acc0 = {0.f}, acc1 = {0.f};
#pragma unroll
    for (int r = 0; r < 16; ++r) { acc0[r] = 0.f; acc1[r] = 0.f; }

    const _Float16* xr0 = xs + (0 * 32 + l31) * 136 + kh * 32;
    const _Float16* xr1 = xs + (1 * 32 + l31) * 136 + kh * 32;

    h8 xc0, xc1, xn0, xn1;
    xc0 = *(const h8*)xr0;       xc1 = *(const h8*)xr1;
    xn0 = *(const h8*)(xr0 + 8); xn1 = *(const h8*)(xr1 + 8);

#pragma unroll
    for (int bb = 0; bb < 4; ++bb) {
#pragma unroll
        for (int u = 0; u < 8; ++u) {
            uint4 cur = ring[u];
            if (bb < 3) ring[u] = bp[(bb * 8 + u + 8) * 256];   // no tail overshoot
            acc0 = mfma32(mk_afrag(xc0[u], ee0), cur, acc0);
            acc1 = mfma32(mk_afrag(xc1[u], ee1), cur, acc1);
        }
        xc0 = xn0; xc1 = xn1;
        if (bb + 2 < 4) {
            xn0 = *(const h8*)(xr0 + (bb + 2) * 8);
            xn1 = *(const h8*)(xr1 + (bb + 2) * 8);
        }
    }

    // C layout (32x32): col = t*32 + l31, row = (r&3) + 8*(r>>2) + 4*half
    const int colG = t * 32 + l31;
#define ROWOF(r) (((r) & 3) + 8 * ((r) >> 2) + 4 * half)

    // ALL waves store f32 partials (2-way bank alias = free)
    {
        float* st = sets + kh * (64 * 128);
#pragma unroll
        for (int r = 0; r < 16; ++r) {
            int row = ROWOF(r);
            st[row * 128 + colG]        = acc0[r];
            st[(row + 32) * 128 + colG] = acc1[r];
        }
    }
    __syncthreads();

    // flat reduce: 1024 threads x 8 outputs, consecutive (conflict-free) reads
    const float inv2048 = 0.022097086912079608f;   // 1/sqrt(128*16)
#pragma unroll
    for (int r = 0; r < 8; ++r) {
        int o = r * 1024 + tid;                    // 0..8191 over 64x128
        float v = sets[o] + sets[o + 8192] + sets[o + 16384] + sets[o + 24576];
        int row = o >> 7, col = o & 127;
        float s = v * inv2048 + b1s[col];
        xs[row * 136 + col] = (_Float16)(s / (1.f + __expf(-s)));
    }
    __syncthreads();   // scs ready; sets free for midp overlay

    // ---------------- Phase 2: (silu(s0) (x) emb) @ W2T  (16x16x32)
    {
        const int ng = wave >> 2, ks = wave & 3;
        const int q = lane >> 4, c = lane & 15;
        const int ih = q >> 1, aodd = q & 1;
        h2 ee[4];
        {
            const float* ep = emb + (size_t)(nodeBase + ng * 16 + c) * 16 + aodd * 8;
            float4 v0 = *(const float4*)ep;
            float4 v1 = *(const float4*)(ep + 4);
            ee[0] = (h2){(_Float16)v0.x, (_Float16)v0.y};
            ee[1] = (h2){(_Float16)v0.z, (_Float16)v0.w};
            ee[2] = (h2){(_Float16)v1.x, (_Float16)v1.y};
            ee[3] = (h2){(_Float16)v1.z, (_Float16)v1.w};
        }
        const _Float16* srow = xs + (ng * 16 + c) * 136;   // col = 2*k2global + ih
        const uint4* b2p = (const uint4*)W2T + lane;
        f32x4 m0 = (f32x4){0.f, 0.f, 0.f, 0.f};
        uint4 wb[4];
#pragma unroll
        for (int u = 0; u < 4; ++u) wb[u] = b2p[(ks * 16 + u) * 64];
#pragma unroll
        for (int k2 = 0; k2 < 16; ++k2) {
            uint4 cur = wb[k2 & 3];
            if (k2 + 4 < 16) wb[k2 & 3] = b2p[(ks * 16 + k2 + 4) * 64];
            _Float16 sv = srow[(ks * 16 + k2) * 2 + ih];
            m0 = mfma16(mk_afrag(sv, ee), cur, m0);
        }
#pragma unroll
        for (int r = 0; r < 4; ++r) {
            int node = ng * 16 + q * 4 + r;
            midp[(ks * 64 + node) * 17 + c] = m0[r];
        }
    }
    __syncthreads();

    // reduce 4 K-quarters; 1024 threads = 64 nodes x 16 cols
    {
        int node = tid >> 4, col = tid & 15;
        float m = midp[node * 17 + col] + midp[(64 + node) * 17 + col]
                + midp[(128 + node) * 17 + col] + midp[(192 + node) * 17 + col];
        mids[node * 17 + col] = m * inv2048 + b2s[col];
    }
    __syncthreads();

    // ---------------- Phase 3: h = silu(mid@W3/4 + b3); out = h@W4/4 + b4
    {
        int n = tid >> 4, jj = tid & 15;
        float a = 0.f;
#pragma unroll
        for (int cc = 0; cc < 16; ++cc) a += mids[n * 17 + cc] * w3s[cc * 16 + jj];
        a = a * 0.25f + b3s[jj];
        float hh = a / (1.f + __expf(-a));
        float po = hh * w4s[jj];
        po += __shfl_xor(po, 1);
        po += __shfl_xor(po, 2);
        po += __shfl_xor(po, 4);
        po += __shfl_xor(po, 8);
        if (jj == 0) out[nodeBase + n] = po * 0.25f + b4s[0];
    }
#undef ROWOF
}

extern "C" void kernel_launch(void* const* d_in, const int* in_sizes, int n_in,
                              void* d_out, int out_size, void* d_ws, size_t ws_size,
                              hipStream_t stream) {
    const float* node_vec = (const float*)d_in[0];
    const float* emb      = (const float*)d_in[1];
    const float* W1       = (const float*)d_in[2];
    const float* b1v      = (const float*)d_in[5];
    const float* W2       = (const float*)d_in[6];
    const float* b2v      = (const float*)d_in[7];
    const float* W3       = (const float*)d_in[8];
    const float* b3v      = (const float*)d_in[9];
    const float* W4       = (const float*)d_in[10];
    const float* b4v      = (const float*)d_in[11];

    _Float16* W1T = (_Float16*)d_ws;          // 128*4*64*8 halves = 512 KB
    _Float16* W2T = W1T + 128 * 4 * 64 * 8;   // 64*512 halves = 64 KB
    float* out = (float*)d_out;

    prep_kernel<<<192, 256, 0, stream>>>(W1, W2, W1T, W2T);
    main_kernel<<<256, 1024, 0, stream>>>(node_vec, emb, W1T, W2T,
                                          b1v, b2v, W3, b3v, W4, b4v, out);
}